// Round 1
// 731.059 us; speedup vs baseline: 1.3543x; 1.3543x over previous
//
#include <hip/hip_runtime.h>
#include <math.h>

#define D 100
#define T 50
#define BB 512
#define NOUT 99999

__device__ __forceinline__ float sigf(float x) { return 1.f / (1.f + expf(-x)); }

// ===========================================================================
// Fused per-batch GGNN + attention kernel. One block per batch (512 blocks).
// LDS: hS (h, later h'), R1 (X1 -> a_in -> r*h -> seqW), R2 (X2 -> a_out -> u)
// Weight-GEMM phases are register-tiled over t (10- or 5-row tiles) so each
// weight quad is loaded ONCE per t-group instead of once per (t,quad) task:
// cuts L2 weight traffic ~10x (was ~12 GB/launch ~= L2 BW ceiling).
// ===========================================================================
__global__ __launch_bounds__(256) void ggnn_fused(
    const float* __restrict__ adj_in, const float* __restrict__ adj_out,
    const float* __restrict__ mask,   const int* __restrict__ item,
    const int* __restrict__ alias_,   const float* __restrict__ emb,
    const float* __restrict__ W_in,   const float* __restrict__ b_in,
    const float* __restrict__ W_out,  const float* __restrict__ b_out,
    const float* __restrict__ gate_k, const float* __restrict__ gate_b,
    const float* __restrict__ cand_k, const float* __restrict__ cand_b,
    const float* __restrict__ w1,     const float* __restrict__ w2,
    const float* __restrict__ v,      const float* __restrict__ nb,
    const float* __restrict__ Bm,     float* __restrict__ y1)
{
    __shared__ float hS[T*D];      // 20 KB
    __shared__ float R1[T*D];      // 20 KB
    __shared__ float R2[T*D];      // 20 KB
    __shared__ float maskS[T+2], vS[D], nbS[D], lastWS[D], coefS[T+2], maS[2*D];
    __shared__ int aliasS[T+2];
    __shared__ int rmidx;

    const int b = blockIdx.x, tid = threadIdx.x;
    const size_t bT = (size_t)b * T;

    // ---- P0: small stages ----
    if (tid < T) {
        aliasS[tid] = alias_[bT + tid];
        maskS[tid]  = mask[bT + tid];
    }
    if (tid >= 64 && tid < 64 + D) {
        int k = tid - 64;
        vS[k] = v[k]; nbS[k] = nb[k];
    }
    // ---- P1: h = emb[item] ----
    for (int idx = tid; idx < T*25; idx += 256) {
        int t = idx / 25, q = idx - t*25;
        int node = item[bT + t];
        *(float4*)&hS[t*D + q*4] = *(const float4*)&emb[(size_t)node*D + q*4];
    }
    __syncthreads();
    if (tid == 0) {
        float s = 0.f;
        for (int t = 0; t < T; ++t) s += maskS[t];
        rmidx = aliasS[(int)s - 1];
    }

    // role decode for the 250 active weight-GEMM threads
    const bool act250 = tid < 250;
    const int tg50  = tid / 50;      // 0..4 valid  (t-group of 10)
    const int rem50 = tid % 50;
    const int cg25  = tid / 25;      // 0..9 valid  (t-group of 5)
    const int jq25  = tid % 25;

    // ---- P2: X1 = h@W_in+b_in -> R1 ; X2 = h@W_out+b_out -> R2 ----
    // thread = (which, jq, tgroup of 10 t); weight quad loaded once per 10 t
    if (act250) {
        const int which = rem50 / 25, jq = rem50 % 25;
        const int t0 = tg50 * 10;
        const float* W  = which ? W_out : W_in;
        const float* bb = which ? b_out : b_in;
        float4 binit = *(const float4*)&bb[jq*4];
        float4 acc[10];
        #pragma unroll
        for (int tt = 0; tt < 10; ++tt) acc[tt] = binit;
        for (int k = 0; k < D; k += 2) {
            float4 wa = *(const float4*)&W[k*D + jq*4];
            float4 wb = *(const float4*)&W[(k+1)*D + jq*4];
            #pragma unroll
            for (int tt = 0; tt < 10; ++tt) {
                float2 a = *(const float2*)&hS[(t0+tt)*D + k];
                acc[tt].x += a.x*wa.x + a.y*wb.x;
                acc[tt].y += a.x*wa.y + a.y*wb.y;
                acc[tt].z += a.x*wa.z + a.y*wb.z;
                acc[tt].w += a.x*wa.w + a.y*wb.w;
            }
        }
        float* dst = which ? R2 : R1;
        #pragma unroll
        for (int tt = 0; tt < 10; ++tt)
            *(float4*)&dst[(t0+tt)*D + jq*4] = acc[tt];
    }
    __syncthreads();

    // ---- P3: a_in = adj_in@X1, a_out = adj_out@X2 (into regs) ----
    float4 eacc[10];
    if (act250) {
        const int which = rem50 / 25, jq = rem50 % 25;
        const int t0 = tg50 * 10;
        const float* adj = which ? adj_out : adj_in;
        const float* Xs  = which ? R2 : R1;
        #pragma unroll
        for (int tt = 0; tt < 10; ++tt) eacc[tt] = make_float4(0.f,0.f,0.f,0.f);
        #pragma unroll 2
        for (int s = 0; s < T; ++s) {
            float4 x = *(const float4*)&Xs[s*D + jq*4];
            const float* ap = &adj[(bT + t0)*T + s];
            #pragma unroll
            for (int tt = 0; tt < 10; ++tt) {
                float a = ap[tt*T];
                eacc[tt].x += a*x.x; eacc[tt].y += a*x.y;
                eacc[tt].z += a*x.z; eacc[tt].w += a*x.w;
            }
        }
    }
    __syncthreads();                 // all X reads done
    // ---- P3b: write a_in -> R1, a_out -> R2 ----
    if (act250) {
        const int which = rem50 / 25, jq = rem50 % 25;
        const int t0 = tg50 * 10;
        float* dst = which ? R2 : R1;
        #pragma unroll
        for (int tt = 0; tt < 10; ++tt)
            *(float4*)&dst[(t0+tt)*D + jq*4] = eacc[tt];
    }
    __syncthreads();

    // ---- P4: gates = sigmoid([a_in|a_out|h] @ gate_k + gate_b) into regs ----
    // thread = (nq 0..49, tgroup of 10 t); 6 weight quads per k-pair, 10 rows
    float4 gacc[10];
    if (act250) {
        const int nq = rem50;
        const int t0 = tg50 * 10;
        float4 ginit = *(const float4*)&gate_b[nq*4];
        #pragma unroll
        for (int tt = 0; tt < 10; ++tt) gacc[tt] = ginit;
        for (int k = 0; k < D; k += 2) {
            float4 g0a = *(const float4*)&gate_k[(size_t)k*200 + nq*4];
            float4 g0b = *(const float4*)&gate_k[(size_t)(k+1)*200 + nq*4];
            float4 g1a = *(const float4*)&gate_k[(size_t)(k+100)*200 + nq*4];
            float4 g1b = *(const float4*)&gate_k[(size_t)(k+101)*200 + nq*4];
            float4 g2a = *(const float4*)&gate_k[(size_t)(k+200)*200 + nq*4];
            float4 g2b = *(const float4*)&gate_k[(size_t)(k+201)*200 + nq*4];
            #pragma unroll
            for (int tt = 0; tt < 10; ++tt) {
                float2 a0 = *(const float2*)&R1[(t0+tt)*D + k];
                float2 a1 = *(const float2*)&R2[(t0+tt)*D + k];
                float2 a2 = *(const float2*)&hS[(t0+tt)*D + k];
                gacc[tt].x += a0.x*g0a.x + a0.y*g0b.x + a1.x*g1a.x + a1.y*g1b.x + a2.x*g2a.x + a2.y*g2b.x;
                gacc[tt].y += a0.x*g0a.y + a0.y*g0b.y + a1.x*g1a.y + a1.y*g1b.y + a2.x*g2a.y + a2.y*g2b.y;
                gacc[tt].z += a0.x*g0a.z + a0.y*g0b.z + a1.x*g1a.z + a1.y*g1b.z + a2.x*g2a.z + a2.y*g2b.z;
                gacc[tt].w += a0.x*g0a.w + a0.y*g0b.w + a1.x*g1a.w + a1.y*g1b.w + a2.x*g2a.w + a2.y*g2b.w;
            }
        }
        #pragma unroll
        for (int tt = 0; tt < 10; ++tt) {
            gacc[tt].x = sigf(gacc[tt].x); gacc[tt].y = sigf(gacc[tt].y);
            gacc[tt].z = sigf(gacc[tt].z); gacc[tt].w = sigf(gacc[tt].w);
        }
    }

    // ---- P5a: cand partial (segments a_in, a_out) into regs ----
    // thread = (jq 0..24, tgroup of 5 t)
    float4 cacc[5];
    if (act250) {
        const int t0 = cg25 * 5;
        float4 cinit = *(const float4*)&cand_b[jq25*4];
        #pragma unroll
        for (int tt = 0; tt < 5; ++tt) cacc[tt] = cinit;
        for (int k = 0; k < D; k += 2) {
            float4 c0a = *(const float4*)&cand_k[(size_t)k*D + jq25*4];
            float4 c0b = *(const float4*)&cand_k[(size_t)(k+1)*D + jq25*4];
            float4 c1a = *(const float4*)&cand_k[(size_t)(k+100)*D + jq25*4];
            float4 c1b = *(const float4*)&cand_k[(size_t)(k+101)*D + jq25*4];
            #pragma unroll
            for (int tt = 0; tt < 5; ++tt) {
                float2 a0 = *(const float2*)&R1[(t0+tt)*D + k];
                float2 a1 = *(const float2*)&R2[(t0+tt)*D + k];
                cacc[tt].x += a0.x*c0a.x + a0.y*c0b.x + a1.x*c1a.x + a1.y*c1b.x;
                cacc[tt].y += a0.x*c0a.y + a0.y*c0b.y + a1.x*c1a.y + a1.y*c1b.y;
                cacc[tt].z += a0.x*c0a.z + a0.y*c0b.z + a1.x*c1a.z + a1.y*c1b.z;
                cacc[tt].w += a0.x*c0a.w + a0.y*c0b.w + a1.x*c1a.w + a1.y*c1b.w;
            }
        }
    }
    __syncthreads();                 // R1/R2 (a_in/a_out) reads done

    // ---- P5b: r-owners write r*h -> R1 ; u-owners write u -> R2 ----
    if (act250) {
        const int nq = rem50;
        const int t0 = tg50 * 10;
        if (nq < 25) {
            #pragma unroll
            for (int tt = 0; tt < 10; ++tt) {
                float4 hh = *(const float4*)&hS[(t0+tt)*D + nq*4];
                float4 g = gacc[tt];
                float4 o; o.x = g.x*hh.x; o.y = g.y*hh.y; o.z = g.z*hh.z; o.w = g.w*hh.w;
                *(float4*)&R1[(t0+tt)*D + nq*4] = o;
            }
        } else {
            #pragma unroll
            for (int tt = 0; tt < 10; ++tt)
                *(float4*)&R2[(t0+tt)*D + (nq-25)*4] = gacc[tt];
        }
    }
    __syncthreads();

    // ---- P5c: cand segment r*h + tanh; fused P7: h' = u*h+(1-u)*c -> hS ----
    if (act250) {
        const int t0 = cg25 * 5;
        for (int k = 0; k < D; k += 2) {
            float4 c2a = *(const float4*)&cand_k[(size_t)(k+200)*D + jq25*4];
            float4 c2b = *(const float4*)&cand_k[(size_t)(k+201)*D + jq25*4];
            #pragma unroll
            for (int tt = 0; tt < 5; ++tt) {
                float2 rh = *(const float2*)&R1[(t0+tt)*D + k];
                cacc[tt].x += rh.x*c2a.x + rh.y*c2b.x;
                cacc[tt].y += rh.x*c2a.y + rh.y*c2b.y;
                cacc[tt].z += rh.x*c2a.z + rh.y*c2b.z;
                cacc[tt].w += rh.x*c2a.w + rh.y*c2b.w;
            }
        }
        #pragma unroll
        for (int tt = 0; tt < 5; ++tt) {
            float4 c4;
            c4.x = tanhf(cacc[tt].x); c4.y = tanhf(cacc[tt].y);
            c4.z = tanhf(cacc[tt].z); c4.w = tanhf(cacc[tt].w);
            float4 u4 = *(const float4*)&R2[(t0+tt)*D + jq25*4];
            float4 hh = *(const float4*)&hS[(t0+tt)*D + jq25*4];
            float4 o;
            o.x = u4.x*hh.x + (1.f-u4.x)*c4.x;
            o.y = u4.y*hh.y + (1.f-u4.y)*c4.y;
            o.z = u4.z*hh.z + (1.f-u4.z)*c4.z;
            o.w = u4.w*hh.w + (1.f-u4.w)*c4.w;
            *(float4*)&hS[(t0+tt)*D + jq25*4] = o;
        }
    }
    __syncthreads();

    // ---- P8: seqW[t] = h'[alias[t]] @ w2 -> R1 ; lastW = h'[rmidx] @ w1 ----
    if (tid < 125) {
        const int sg = tid / 25, jq = tid % 25;
        const int t0 = sg * 10;
        float4 sacc[10];
        #pragma unroll
        for (int tt = 0; tt < 10; ++tt) sacc[tt] = make_float4(0.f,0.f,0.f,0.f);
        int at[10];
        #pragma unroll
        for (int tt = 0; tt < 10; ++tt) at[tt] = aliasS[t0+tt];
        for (int k = 0; k < D; k += 2) {
            float4 wa = *(const float4*)&w2[(size_t)k*D + jq*4];
            float4 wb = *(const float4*)&w2[(size_t)(k+1)*D + jq*4];
            #pragma unroll
            for (int tt = 0; tt < 10; ++tt) {
                float2 a = *(const float2*)&hS[at[tt]*D + k];
                sacc[tt].x += a.x*wa.x + a.y*wb.x;
                sacc[tt].y += a.x*wa.y + a.y*wb.y;
                sacc[tt].z += a.x*wa.z + a.y*wb.z;
                sacc[tt].w += a.x*wa.w + a.y*wb.w;
            }
        }
        #pragma unroll
        for (int tt = 0; tt < 10; ++tt)
            *(float4*)&R1[(t0+tt)*D + jq*4] = sacc[tt];
    } else if (tid >= 128 && tid < 153) {
        const int jq = tid - 128;
        const int lid = rmidx;
        float4 acc = make_float4(0.f,0.f,0.f,0.f);
        for (int k = 0; k < D; k += 2) {
            float4 wa = *(const float4*)&w1[(size_t)k*D + jq*4];
            float4 wb = *(const float4*)&w1[(size_t)(k+1)*D + jq*4];
            float2 a = *(const float2*)&hS[lid*D + k];
            acc.x += a.x*wa.x + a.y*wb.x;
            acc.y += a.x*wa.y + a.y*wb.y;
            acc.z += a.x*wa.z + a.y*wb.z;
            acc.w += a.x*wa.w + a.y*wb.w;
        }
        *(float4*)&lastWS[jq*4] = acc;
    }
    __syncthreads();

    // ---- P9: coef[t] = mask[t] * sum_k v[k]*sigmoid(lastW[k]+seqW[t][k]+nb[k])
    if (tid < T) {
        float s = 0.f;
        #pragma unroll 4
        for (int k = 0; k < D; ++k) {
            float x = lastWS[k] + R1[tid*D + k] + nbS[k];
            s += vS[k] * sigf(x);
        }
        coefS[tid] = s * maskS[tid];
    }
    __syncthreads();
    // ---- P10: ma = [sum_t coef[t]*h'[alias[t]], lastW] ----
    if (tid < 25) {
        float4 acc = make_float4(0.f,0.f,0.f,0.f);
        #pragma unroll 5
        for (int t = 0; t < T; ++t) {
            float c = coefS[t];
            float4 hh = *(const float4*)&hS[aliasS[t]*D + tid*4];
            acc.x += c*hh.x; acc.y += c*hh.y; acc.z += c*hh.z; acc.w += c*hh.w;
        }
        *(float4*)&maS[tid*4] = acc;
    } else if (tid >= 32 && tid < 57) {
        int j4 = tid - 32;
        *(float4*)&maS[D + j4*4] = *(const float4*)&lastWS[j4*4];
    }
    __syncthreads();
    // ---- P11: y1[b] = ma @ B_mat ----
    if (tid < 25) {
        float4 acc = make_float4(0.f,0.f,0.f,0.f);
        #pragma unroll 4
        for (int k = 0; k < 2*D; ++k) {
            float a = maS[k];
            float4 w = *(const float4*)&Bm[(size_t)k*D + tid*4];
            acc.x += a*w.x; acc.y += a*w.y; acc.z += a*w.z; acc.w += a*w.w;
        }
        *(float4*)&y1[(size_t)b*D + tid*4] = acc;
    }
}

// ===========================================================================
// logits[512, 99999] = y1[512,100] @ emb[1:,:]^T
// 128x128 tile, 8x8/thread. Two K-chunks (48 / 52) with register prefetch of
// chunk 1 during chunk 0 compute -> 3 barriers total, staging hidden.
// LDS 54 KB -> up to 3 blocks/CU. Grid (n-tiles, m-tiles): consecutive blocks
// = different n on different XCDs.
// ===========================================================================
__global__ __launch_bounds__(256) void gemm_big(
    const float* __restrict__ y1,
    const float* __restrict__ emb,
    float* __restrict__ out)
{
    __shared__ float As[128*52];   // [m][k_local]
    __shared__ float Bs[52*132];   // [k_local][n]
    int tid = threadIdx.x;
    int tx = tid & 15, ty = tid >> 4;
    int n0 = blockIdx.x * 128;
    int m0 = blockIdx.y * 128;
    float acc[8][8] = {};

    // stage A chunk0 (k 0..47): 128 m x 12 f4
    for (int idx = tid; idx < 128*12; idx += 256) {
        int m = idx / 12, q = idx - m*12;
        *(float4*)&As[m*52 + q*4] = *(const float4*)&y1[(size_t)(m0+m)*D + q*4];
    }
    // stage B chunk0: k 0..47 transposed from emb
    for (int idx = tid; idx < 128*12; idx += 256) {
        int n = idx / 12, q = idx - n*12;
        int gn = n0 + n;
        float4 vv = make_float4(0.f,0.f,0.f,0.f);
        if (gn < NOUT) vv = *(const float4*)&emb[(size_t)(gn+1)*D + q*4];
        Bs[(q*4+0)*132 + n] = vv.x;
        Bs[(q*4+1)*132 + n] = vv.y;
        Bs[(q*4+2)*132 + n] = vv.z;
        Bs[(q*4+3)*132 + n] = vv.w;
    }
    __syncthreads();
    // prefetch chunk1 (k 48..99, 13 f4) into regs
    float4 pfa[7], pfb[7];
    int na = 0;
    for (int idx = tid; idx < 128*13; idx += 256, ++na) {
        int m = idx / 13, q = idx - m*13;
        pfa[na] = *(const float4*)&y1[(size_t)(m0+m)*D + 48 + q*4];
    }
    int nbc = 0;
    for (int idx = tid; idx < 128*13; idx += 256, ++nbc) {
        int n = idx / 13, q = idx - n*13;
        int gn = n0 + n;
        float4 vv = make_float4(0.f,0.f,0.f,0.f);
        if (gn < NOUT) vv = *(const float4*)&emb[(size_t)(gn+1)*D + 48 + q*4];
        pfb[nbc] = vv;
    }
    // compute chunk0: 24 kk-steps
    #pragma unroll 4
    for (int kk = 0; kk < 48; kk += 2) {
        float2 a[8];
        #pragma unroll
        for (int i = 0; i < 8; ++i)
            a[i] = *(const float2*)&As[(ty + i*16)*52 + kk];
        float4 b00 = *(const float4*)&Bs[kk*132 + tx*4];
        float4 b01 = *(const float4*)&Bs[kk*132 + 64 + tx*4];
        float4 b10 = *(const float4*)&Bs[(kk+1)*132 + tx*4];
        float4 b11 = *(const float4*)&Bs[(kk+1)*132 + 64 + tx*4];
        #pragma unroll
        for (int i = 0; i < 8; ++i) {
            acc[i][0] += a[i].x*b00.x; acc[i][1] += a[i].x*b00.y;
            acc[i][2] += a[i].x*b00.z; acc[i][3] += a[i].x*b00.w;
            acc[i][4] += a[i].x*b01.x; acc[i][5] += a[i].x*b01.y;
            acc[i][6] += a[i].x*b01.z; acc[i][7] += a[i].x*b01.w;
            acc[i][0] += a[i].y*b10.x; acc[i][1] += a[i].y*b10.y;
            acc[i][2] += a[i].y*b10.z; acc[i][3] += a[i].y*b10.w;
            acc[i][4] += a[i].y*b11.x; acc[i][5] += a[i].y*b11.y;
            acc[i][6] += a[i].y*b11.z; acc[i][7] += a[i].y*b11.w;
        }
    }
    __syncthreads();
    // write chunk1 regs -> LDS
    na = 0;
    for (int idx = tid; idx < 128*13; idx += 256, ++na) {
        int m = idx / 13, q = idx - m*13;
        *(float4*)&As[m*52 + q*4] = pfa[na];
    }
    nbc = 0;
    for (int idx = tid; idx < 128*13; idx += 256, ++nbc) {
        int n = idx / 13, q = idx - n*13;
        float4 vv = pfb[nbc];
        Bs[(q*4+0)*132 + n] = vv.x;
        Bs[(q*4+1)*132 + n] = vv.y;
        Bs[(q*4+2)*132 + n] = vv.z;
        Bs[(q*4+3)*132 + n] = vv.w;
    }
    __syncthreads();
    // compute chunk1: 26 kk-steps
    #pragma unroll 4
    for (int kk = 0; kk < 52; kk += 2) {
        float2 a[8];
        #pragma unroll
        for (int i = 0; i < 8; ++i)
            a[i] = *(const float2*)&As[(ty + i*16)*52 + kk];
        float4 b00 = *(const float4*)&Bs[kk*132 + tx*4];
        float4 b01 = *(const float4*)&Bs[kk*132 + 64 + tx*4];
        float4 b10 = *(const float4*)&Bs[(kk+1)*132 + tx*4];
        float4 b11 = *(const float4*)&Bs[(kk+1)*132 + 64 + tx*4];
        #pragma unroll
        for (int i = 0; i < 8; ++i) {
            acc[i][0] += a[i].x*b00.x; acc[i][1] += a[i].x*b00.y;
            acc[i][2] += a[i].x*b00.z; acc[i][3] += a[i].x*b00.w;
            acc[i][4] += a[i].x*b01.x; acc[i][5] += a[i].x*b01.y;
            acc[i][6] += a[i].x*b01.z; acc[i][7] += a[i].x*b01.w;
            acc[i][0] += a[i].y*b10.x; acc[i][1] += a[i].y*b10.y;
            acc[i][2] += a[i].y*b10.z; acc[i][3] += a[i].y*b10.w;
            acc[i][4] += a[i].y*b11.x; acc[i][5] += a[i].y*b11.y;
            acc[i][6] += a[i].y*b11.z; acc[i][7] += a[i].y*b11.w;
        }
    }
    // epilogue
    #pragma unroll
    for (int i = 0; i < 8; ++i) {
        int m = m0 + ty + i*16;
        #pragma unroll
        for (int half = 0; half < 2; ++half) {
            int nA = n0 + half*64 + tx*4;
            float* cp = &out[(size_t)m*NOUT + nA];
            #pragma unroll
            for (int q = 0; q < 4; ++q)
                if (nA + q < NOUT) cp[q] = acc[i][half*4+q];
        }
    }
}

// ---------------------------------------------------------------------------
extern "C" void kernel_launch(void* const* d_in, const int* in_sizes, int n_in,
                              void* d_out, int out_size, void* d_ws, size_t ws_size,
                              hipStream_t stream)
{
    const float* adj_in  = (const float*)d_in[0];
    const float* adj_out = (const float*)d_in[1];
    const float* mask    = (const float*)d_in[2];
    const int*   item    = (const int*)  d_in[3];
    const int*   alias_  = (const int*)  d_in[4];
    const float* emb     = (const float*)d_in[6];
    const float* W_in    = (const float*)d_in[7];
    const float* b_in    = (const float*)d_in[8];
    const float* W_out   = (const float*)d_in[9];
    const float* b_out   = (const float*)d_in[10];
    const float* gate_k  = (const float*)d_in[11];
    const float* gate_b  = (const float*)d_in[12];
    const float* cand_k  = (const float*)d_in[13];
    const float* cand_b  = (const float*)d_in[14];
    const float* w1      = (const float*)d_in[15];
    const float* w2      = (const float*)d_in[16];
    const float* v       = (const float*)d_in[17];
    const float* nb      = (const float*)d_in[18];
    const float* Bm      = (const float*)d_in[19];
    float* out = (float*)d_out;
    float* y1  = (float*)d_ws;   // [512,100]

    ggnn_fused<<<BB, 256, 0, stream>>>(
        adj_in, adj_out, mask, item, alias_, emb,
        W_in, b_in, W_out, b_out, gate_k, gate_b, cand_k, cand_b,
        w1, w2, v, nb, Bm, y1);

    gemm_big<<<dim3((NOUT + 127)/128, 4), 256, 0, stream>>>(y1, emb, out);
}

// Round 4
// 646.900 us; speedup vs baseline: 1.5305x; 1.1301x over previous
//
#include <hip/hip_runtime.h>
#include <math.h>

#define D 100
#define T 50
#define BB 512
#define NOUT 99999

__device__ __forceinline__ float sigf(float x) { return 1.f / (1.f + expf(-x)); }

// ===========================================================================
// Fused per-batch GGNN + attention kernel. One block per batch (512 blocks).
// LDS: hS (h, later h'), R1 (X1 -> a_in -> r*h -> seqW), R2 (X2 -> a_out -> u)
// Weight-GEMM phases are register-tiled over t (10- or 5-row tiles) so each
// weight quad is loaded ONCE per t-group instead of once per (t,quad) task:
// cuts L2 weight traffic ~10x (was ~12 GB/launch ~= L2 BW ceiling).
// ===========================================================================
__global__ __launch_bounds__(256) void ggnn_fused(
    const float* __restrict__ adj_in, const float* __restrict__ adj_out,
    const float* __restrict__ mask,   const int* __restrict__ item,
    const int* __restrict__ alias_,   const float* __restrict__ emb,
    const float* __restrict__ W_in,   const float* __restrict__ b_in,
    const float* __restrict__ W_out,  const float* __restrict__ b_out,
    const float* __restrict__ gate_k, const float* __restrict__ gate_b,
    const float* __restrict__ cand_k, const float* __restrict__ cand_b,
    const float* __restrict__ w1,     const float* __restrict__ w2,
    const float* __restrict__ v,      const float* __restrict__ nb,
    const float* __restrict__ Bm,     float* __restrict__ y1)
{
    __shared__ float hS[T*D];      // 20 KB
    __shared__ float R1[T*D];      // 20 KB
    __shared__ float R2[T*D];      // 20 KB
    __shared__ float maskS[T+2], vS[D], nbS[D], lastWS[D], coefS[T+2], maS[2*D];
    __shared__ int aliasS[T+2];
    __shared__ int rmidx;

    const int b = blockIdx.x, tid = threadIdx.x;
    const size_t bT = (size_t)b * T;

    // ---- P0: small stages ----
    if (tid < T) {
        aliasS[tid] = alias_[bT + tid];
        maskS[tid]  = mask[bT + tid];
    }
    if (tid >= 64 && tid < 64 + D) {
        int k = tid - 64;
        vS[k] = v[k]; nbS[k] = nb[k];
    }
    // ---- P1: h = emb[item] ----
    for (int idx = tid; idx < T*25; idx += 256) {
        int t = idx / 25, q = idx - t*25;
        int node = item[bT + t];
        *(float4*)&hS[t*D + q*4] = *(const float4*)&emb[(size_t)node*D + q*4];
    }
    __syncthreads();
    if (tid == 0) {
        float s = 0.f;
        for (int t = 0; t < T; ++t) s += maskS[t];
        rmidx = aliasS[(int)s - 1];
    }

    // role decode for the 250 active weight-GEMM threads
    const bool act250 = tid < 250;
    const int tg50  = tid / 50;      // 0..4 valid  (t-group of 10)
    const int rem50 = tid % 50;
    const int cg25  = tid / 25;      // 0..9 valid  (t-group of 5)
    const int jq25  = tid % 25;

    // ---- P2: X1 = h@W_in+b_in -> R1 ; X2 = h@W_out+b_out -> R2 ----
    // thread = (which, jq, tgroup of 10 t); weight quad loaded once per 10 t
    if (act250) {
        const int which = rem50 / 25, jq = rem50 % 25;
        const int t0 = tg50 * 10;
        const float* W  = which ? W_out : W_in;
        const float* bb = which ? b_out : b_in;
        float4 binit = *(const float4*)&bb[jq*4];
        float4 acc[10];
        #pragma unroll
        for (int tt = 0; tt < 10; ++tt) acc[tt] = binit;
        for (int k = 0; k < D; k += 2) {
            float4 wa = *(const float4*)&W[k*D + jq*4];
            float4 wb = *(const float4*)&W[(k+1)*D + jq*4];
            #pragma unroll
            for (int tt = 0; tt < 10; ++tt) {
                float2 a = *(const float2*)&hS[(t0+tt)*D + k];
                acc[tt].x += a.x*wa.x + a.y*wb.x;
                acc[tt].y += a.x*wa.y + a.y*wb.y;
                acc[tt].z += a.x*wa.z + a.y*wb.z;
                acc[tt].w += a.x*wa.w + a.y*wb.w;
            }
        }
        float* dst = which ? R2 : R1;
        #pragma unroll
        for (int tt = 0; tt < 10; ++tt)
            *(float4*)&dst[(t0+tt)*D + jq*4] = acc[tt];
    }
    __syncthreads();

    // ---- P3: a_in = adj_in@X1, a_out = adj_out@X2 (into regs) ----
    float4 eacc[10];
    if (act250) {
        const int which = rem50 / 25, jq = rem50 % 25;
        const int t0 = tg50 * 10;
        const float* adj = which ? adj_out : adj_in;
        const float* Xs  = which ? R2 : R1;
        #pragma unroll
        for (int tt = 0; tt < 10; ++tt) eacc[tt] = make_float4(0.f,0.f,0.f,0.f);
        #pragma unroll 2
        for (int s = 0; s < T; ++s) {
            float4 x = *(const float4*)&Xs[s*D + jq*4];
            const float* ap = &adj[(bT + t0)*T + s];
            #pragma unroll
            for (int tt = 0; tt < 10; ++tt) {
                float a = ap[tt*T];
                eacc[tt].x += a*x.x; eacc[tt].y += a*x.y;
                eacc[tt].z += a*x.z; eacc[tt].w += a*x.w;
            }
        }
    }
    __syncthreads();                 // all X reads done
    // ---- P3b: write a_in -> R1, a_out -> R2 ----
    if (act250) {
        const int which = rem50 / 25, jq = rem50 % 25;
        const int t0 = tg50 * 10;
        float* dst = which ? R2 : R1;
        #pragma unroll
        for (int tt = 0; tt < 10; ++tt)
            *(float4*)&dst[(t0+tt)*D + jq*4] = eacc[tt];
    }
    __syncthreads();

    // ---- P4: gates = sigmoid([a_in|a_out|h] @ gate_k + gate_b) into regs ----
    // thread = (nq 0..49, tgroup of 10 t); 6 weight quads per k-pair, 10 rows
    float4 gacc[10];
    if (act250) {
        const int nq = rem50;
        const int t0 = tg50 * 10;
        float4 ginit = *(const float4*)&gate_b[nq*4];
        #pragma unroll
        for (int tt = 0; tt < 10; ++tt) gacc[tt] = ginit;
        for (int k = 0; k < D; k += 2) {
            float4 g0a = *(const float4*)&gate_k[(size_t)k*200 + nq*4];
            float4 g0b = *(const float4*)&gate_k[(size_t)(k+1)*200 + nq*4];
            float4 g1a = *(const float4*)&gate_k[(size_t)(k+100)*200 + nq*4];
            float4 g1b = *(const float4*)&gate_k[(size_t)(k+101)*200 + nq*4];
            float4 g2a = *(const float4*)&gate_k[(size_t)(k+200)*200 + nq*4];
            float4 g2b = *(const float4*)&gate_k[(size_t)(k+201)*200 + nq*4];
            #pragma unroll
            for (int tt = 0; tt < 10; ++tt) {
                float2 a0 = *(const float2*)&R1[(t0+tt)*D + k];
                float2 a1 = *(const float2*)&R2[(t0+tt)*D + k];
                float2 a2 = *(const float2*)&hS[(t0+tt)*D + k];
                gacc[tt].x += a0.x*g0a.x + a0.y*g0b.x + a1.x*g1a.x + a1.y*g1b.x + a2.x*g2a.x + a2.y*g2b.x;
                gacc[tt].y += a0.x*g0a.y + a0.y*g0b.y + a1.x*g1a.y + a1.y*g1b.y + a2.x*g2a.y + a2.y*g2b.y;
                gacc[tt].z += a0.x*g0a.z + a0.y*g0b.z + a1.x*g1a.z + a1.y*g1b.z + a2.x*g2a.z + a2.y*g2b.z;
                gacc[tt].w += a0.x*g0a.w + a0.y*g0b.w + a1.x*g1a.w + a1.y*g1b.w + a2.x*g2a.w + a2.y*g2b.w;
            }
        }
        #pragma unroll
        for (int tt = 0; tt < 10; ++tt) {
            gacc[tt].x = sigf(gacc[tt].x); gacc[tt].y = sigf(gacc[tt].y);
            gacc[tt].z = sigf(gacc[tt].z); gacc[tt].w = sigf(gacc[tt].w);
        }
    }

    // ---- P5a: cand partial (segments a_in, a_out) into regs ----
    // thread = (jq 0..24, tgroup of 5 t)
    float4 cacc[5];
    if (act250) {
        const int t0 = cg25 * 5;
        float4 cinit = *(const float4*)&cand_b[jq25*4];
        #pragma unroll
        for (int tt = 0; tt < 5; ++tt) cacc[tt] = cinit;
        for (int k = 0; k < D; k += 2) {
            float4 c0a = *(const float4*)&cand_k[(size_t)k*D + jq25*4];
            float4 c0b = *(const float4*)&cand_k[(size_t)(k+1)*D + jq25*4];
            float4 c1a = *(const float4*)&cand_k[(size_t)(k+100)*D + jq25*4];
            float4 c1b = *(const float4*)&cand_k[(size_t)(k+101)*D + jq25*4];
            #pragma unroll
            for (int tt = 0; tt < 5; ++tt) {
                float2 a0 = *(const float2*)&R1[(t0+tt)*D + k];
                float2 a1 = *(const float2*)&R2[(t0+tt)*D + k];
                cacc[tt].x += a0.x*c0a.x + a0.y*c0b.x + a1.x*c1a.x + a1.y*c1b.x;
                cacc[tt].y += a0.x*c0a.y + a0.y*c0b.y + a1.x*c1a.y + a1.y*c1b.y;
                cacc[tt].z += a0.x*c0a.z + a0.y*c0b.z + a1.x*c1a.z + a1.y*c1b.z;
                cacc[tt].w += a0.x*c0a.w + a0.y*c0b.w + a1.x*c1a.w + a1.y*c1b.w;
            }
        }
    }
    __syncthreads();                 // R1/R2 (a_in/a_out) reads done

    // ---- P5b: r-owners write r*h -> R1 ; u-owners write u -> R2 ----
    if (act250) {
        const int nq = rem50;
        const int t0 = tg50 * 10;
        if (nq < 25) {
            #pragma unroll
            for (int tt = 0; tt < 10; ++tt) {
                float4 hh = *(const float4*)&hS[(t0+tt)*D + nq*4];
                float4 g = gacc[tt];
                float4 o; o.x = g.x*hh.x; o.y = g.y*hh.y; o.z = g.z*hh.z; o.w = g.w*hh.w;
                *(float4*)&R1[(t0+tt)*D + nq*4] = o;
            }
        } else {
            #pragma unroll
            for (int tt = 0; tt < 10; ++tt)
                *(float4*)&R2[(t0+tt)*D + (nq-25)*4] = gacc[tt];
        }
    }
    __syncthreads();

    // ---- P5c: cand segment r*h + tanh; fused P7: h' = u*h+(1-u)*c -> hS ----
    if (act250) {
        const int t0 = cg25 * 5;
        for (int k = 0; k < D; k += 2) {
            float4 c2a = *(const float4*)&cand_k[(size_t)(k+200)*D + jq25*4];
            float4 c2b = *(const float4*)&cand_k[(size_t)(k+201)*D + jq25*4];
            #pragma unroll
            for (int tt = 0; tt < 5; ++tt) {
                float2 rh = *(const float2*)&R1[(t0+tt)*D + k];
                cacc[tt].x += rh.x*c2a.x + rh.y*c2b.x;
                cacc[tt].y += rh.x*c2a.y + rh.y*c2b.y;
                cacc[tt].z += rh.x*c2a.z + rh.y*c2b.z;
                cacc[tt].w += rh.x*c2a.w + rh.y*c2b.w;
            }
        }
        #pragma unroll
        for (int tt = 0; tt < 5; ++tt) {
            float4 c4;
            c4.x = tanhf(cacc[tt].x); c4.y = tanhf(cacc[tt].y);
            c4.z = tanhf(cacc[tt].z); c4.w = tanhf(cacc[tt].w);
            float4 u4 = *(const float4*)&R2[(t0+tt)*D + jq25*4];
            float4 hh = *(const float4*)&hS[(t0+tt)*D + jq25*4];
            float4 o;
            o.x = u4.x*hh.x + (1.f-u4.x)*c4.x;
            o.y = u4.y*hh.y + (1.f-u4.y)*c4.y;
            o.z = u4.z*hh.z + (1.f-u4.z)*c4.z;
            o.w = u4.w*hh.w + (1.f-u4.w)*c4.w;
            *(float4*)&hS[(t0+tt)*D + jq25*4] = o;
        }
    }
    __syncthreads();

    // ---- P8: seqW[t] = h'[alias[t]] @ w2 -> R1 ; lastW = h'[rmidx] @ w1 ----
    if (tid < 125) {
        const int sg = tid / 25, jq = tid % 25;
        const int t0 = sg * 10;
        float4 sacc[10];
        #pragma unroll
        for (int tt = 0; tt < 10; ++tt) sacc[tt] = make_float4(0.f,0.f,0.f,0.f);
        int at[10];
        #pragma unroll
        for (int tt = 0; tt < 10; ++tt) at[tt] = aliasS[t0+tt];
        for (int k = 0; k < D; k += 2) {
            float4 wa = *(const float4*)&w2[(size_t)k*D + jq*4];
            float4 wb = *(const float4*)&w2[(size_t)(k+1)*D + jq*4];
            #pragma unroll
            for (int tt = 0; tt < 10; ++tt) {
                float2 a = *(const float2*)&hS[at[tt]*D + k];
                sacc[tt].x += a.x*wa.x + a.y*wb.x;
                sacc[tt].y += a.x*wa.y + a.y*wb.y;
                sacc[tt].z += a.x*wa.z + a.y*wb.z;
                sacc[tt].w += a.x*wa.w + a.y*wb.w;
            }
        }
        #pragma unroll
        for (int tt = 0; tt < 10; ++tt)
            *(float4*)&R1[(t0+tt)*D + jq*4] = sacc[tt];
    } else if (tid >= 128 && tid < 153) {
        const int jq = tid - 128;
        const int lid = rmidx;
        float4 acc = make_float4(0.f,0.f,0.f,0.f);
        for (int k = 0; k < D; k += 2) {
            float4 wa = *(const float4*)&w1[(size_t)k*D + jq*4];
            float4 wb = *(const float4*)&w1[(size_t)(k+1)*D + jq*4];
            float2 a = *(const float2*)&hS[lid*D + k];
            acc.x += a.x*wa.x + a.y*wb.x;
            acc.y += a.x*wa.y + a.y*wb.y;
            acc.z += a.x*wa.z + a.y*wb.z;
            acc.w += a.x*wa.w + a.y*wb.w;
        }
        *(float4*)&lastWS[jq*4] = acc;
    }
    __syncthreads();

    // ---- P9: coef[t] = mask[t] * sum_k v[k]*sigmoid(lastW[k]+seqW[t][k]+nb[k])
    if (tid < T) {
        float s = 0.f;
        #pragma unroll 4
        for (int k = 0; k < D; ++k) {
            float x = lastWS[k] + R1[tid*D + k] + nbS[k];
            s += vS[k] * sigf(x);
        }
        coefS[tid] = s * maskS[tid];
    }
    __syncthreads();
    // ---- P10: ma = [sum_t coef[t]*h'[alias[t]], lastW] ----
    if (tid < 25) {
        float4 acc = make_float4(0.f,0.f,0.f,0.f);
        #pragma unroll 5
        for (int t = 0; t < T; ++t) {
            float c = coefS[t];
            float4 hh = *(const float4*)&hS[aliasS[t]*D + tid*4];
            acc.x += c*hh.x; acc.y += c*hh.y; acc.z += c*hh.z; acc.w += c*hh.w;
        }
        *(float4*)&maS[tid*4] = acc;
    } else if (tid >= 32 && tid < 57) {
        int j4 = tid - 32;
        *(float4*)&maS[D + j4*4] = *(const float4*)&lastWS[j4*4];
    }
    __syncthreads();
    // ---- P11: y1[b] = ma @ B_mat ----
    if (tid < 25) {
        float4 acc = make_float4(0.f,0.f,0.f,0.f);
        #pragma unroll 4
        for (int k = 0; k < 2*D; ++k) {
            float a = maS[k];
            float4 w = *(const float4*)&Bm[(size_t)k*D + tid*4];
            acc.x += a*w.x; acc.y += a*w.y; acc.z += a*w.z; acc.w += a*w.w;
        }
        *(float4*)&y1[(size_t)b*D + tid*4] = acc;
    }
}

// ===========================================================================
// logits[512, 99999] = y1[512,100] @ emb[1:,:]^T
// B-stationary: one block per 128-col n-tile x 256-row m-half.
// B tile (full K=100) staged ONCE in LDS (52.8 KB -> 3 blocks/CU), then 2
// m-chunks of 128 rows computed against it -> emb fetched 2x total (80 MB)
// instead of 4x. A (y1, 200 KB) read directly from L2 via 16-lane broadcast
// loads, register double-buffered -> no A LDS needed.
// Thread owns cols {tx, tx+16, tx+32, tx+48} per 64-half so every store
// instruction writes 64 B contiguous per ty-group (fixes the write
// amplification: WRITE_SIZE was 374 MB vs 205 ideal with strided scalars).
// ===========================================================================
#define LDB 132   // reads are tx-contiguous (conflict-free); 52.8 KB total

#define GB_COMPUTE(Ab, kbase) do {                                            \
    _Pragma("unroll")                                                         \
    for (int kk = 0; kk < 4; ++kk) {                                          \
        float bq[8];                                                          \
        _Pragma("unroll")                                                     \
        for (int j = 0; j < 8; ++j)                                           \
            bq[j] = Bs[(kbase + kk)*LDB + (j>>2)*64 + (j&3)*16 + tx];         \
        _Pragma("unroll")                                                     \
        for (int i = 0; i < 8; ++i) {                                         \
            float a_ = kk==0 ? Ab[i].x : kk==1 ? Ab[i].y :                    \
                       kk==2 ? Ab[i].z : Ab[i].w;                             \
            _Pragma("unroll")                                                 \
            for (int j = 0; j < 8; ++j)                                       \
                acc[i][j] += a_ * bq[j];                                      \
        }                                                                     \
    }                                                                         \
} while (0)

__global__ __launch_bounds__(256) void gemm_big(
    const float* __restrict__ y1,
    const float* __restrict__ emb,
    float* __restrict__ out)
{
    __shared__ float Bs[100*LDB];          // 52.8 KB
    const int tid = threadIdx.x;
    const int tx = tid & 15, ty = tid >> 4;
    const int n0 = blockIdx.x * 128;

    // stage B: cols n0..n0+127, k=0..99, transposed to Bs[k][n_local]
    for (int idx = tid; idx < 128*25; idx += 256) {
        int n = idx / 25, q = idx - n*25;
        int gn = n0 + n;
        float4 vv = make_float4(0.f,0.f,0.f,0.f);
        if (gn < NOUT) vv = *(const float4*)&emb[(size_t)(gn+1)*D + q*4];
        Bs[(q*4+0)*LDB + n] = vv.x;
        Bs[(q*4+1)*LDB + n] = vv.y;
        Bs[(q*4+2)*LDB + n] = vv.z;
        Bs[(q*4+3)*LDB + n] = vv.w;
    }
    __syncthreads();

    float acc[8][8];
    float4 A0[8], A1[8];

    #pragma unroll 1
    for (int mc = 0; mc < 2; ++mc) {
        const int m0 = blockIdx.y * 256 + mc * 128;

        #pragma unroll
        for (int i = 0; i < 8; ++i)
            #pragma unroll
            for (int j = 0; j < 8; ++j) acc[i][j] = 0.f;

        #pragma unroll
        for (int i = 0; i < 8; ++i)
            A0[i] = *(const float4*)&y1[(size_t)(m0 + ty + i*16)*D + 0];

        int k = 0;
        #pragma unroll 1
        for (int it = 0; it < 12; ++it, k += 8) {
            #pragma unroll
            for (int i = 0; i < 8; ++i)
                A1[i] = *(const float4*)&y1[(size_t)(m0 + ty + i*16)*D + k + 4];
            GB_COMPUTE(A0, k);
            #pragma unroll
            for (int i = 0; i < 8; ++i)
                A0[i] = *(const float4*)&y1[(size_t)(m0 + ty + i*16)*D + k + 8];
            GB_COMPUTE(A1, k + 4);
        }
        GB_COMPUTE(A0, 96);   // k = 96..99 tail

        // store: each instr = 16 consecutive lanes -> 64 B contiguous/row
        #pragma unroll
        for (int i = 0; i < 8; ++i) {
            size_t row = (size_t)(m0 + ty + i*16) * NOUT;
            #pragma unroll
            for (int h = 0; h < 2; ++h)
                #pragma unroll
                for (int q = 0; q < 4; ++q) {
                    int n = n0 + h*64 + q*16 + tx;
                    if (n < NOUT) out[row + n] = acc[i][h*4+q];
                }
        }
    }
}

// ---------------------------------------------------------------------------
extern "C" void kernel_launch(void* const* d_in, const int* in_sizes, int n_in,
                              void* d_out, int out_size, void* d_ws, size_t ws_size,
                              hipStream_t stream)
{
    const float* adj_in  = (const float*)d_in[0];
    const float* adj_out = (const float*)d_in[1];
    const float* mask    = (const float*)d_in[2];
    const int*   item    = (const int*)  d_in[3];
    const int*   alias_  = (const int*)  d_in[4];
    const float* emb     = (const float*)d_in[6];
    const float* W_in    = (const float*)d_in[7];
    const float* b_in    = (const float*)d_in[8];
    const float* W_out   = (const float*)d_in[9];
    const float* b_out   = (const float*)d_in[10];
    const float* gate_k  = (const float*)d_in[11];
    const float* gate_b  = (const float*)d_in[12];
    const float* cand_k  = (const float*)d_in[13];
    const float* cand_b  = (const float*)d_in[14];
    const float* w1      = (const float*)d_in[15];
    const float* w2      = (const float*)d_in[16];
    const float* v       = (const float*)d_in[17];
    const float* nb      = (const float*)d_in[18];
    const float* Bm      = (const float*)d_in[19];
    float* out = (float*)d_out;
    float* y1  = (float*)d_ws;   // [512,100]

    ggnn_fused<<<BB, 256, 0, stream>>>(
        adj_in, adj_out, mask, item, alias_, emb,
        W_in, b_in, W_out, b_out, gate_k, gate_b, cand_k, cand_b,
        w1, w2, v, nb, Bm, y1);

    gemm_big<<<dim3((NOUT + 127)/128, 2), 256, 0, stream>>>(y1, emb, out);
}